// Round 5
// baseline (178.001 us; speedup 1.0000x reference)
//
#include <hip/hip_runtime.h>
#include <hip/hip_bf16.h>
#include <math.h>

// Problem constants (PoseMixtureVAE)
#define N_BATCH 4096
#define FRAME   267
#define LATENT  32
#define HIDDEN  256
#define GATE_H  64
#define EXPERTS 6
// Kpads: [x|c]=534->544 (17 ksteps), [x|h]=523->544 (17), [z|c]=299->320 (10),
//        [z|h]=288 (9 exactly), gate hidden 64 (2)

typedef __hip_bfloat16 bf16;
typedef __bf16  bf16x8 __attribute__((ext_vector_type(8)));
typedef float   f32x4  __attribute__((ext_vector_type(4)));

__device__ __forceinline__ float eluf(float v) { return (v > 0.f) ? v : (expf(v) - 1.f); }

#define MFMA(a, b, p) __builtin_amdgcn_mfma_f32_16x16x32_bf16((a), (b), (p), 0, 0, 0)

struct WEnt { const float* src; bf16* dst; int K, M, Mtot, mOff, Ksteps, Mtiles, cum; };
struct WTab { WEnt e[10]; int total; };

// ---------------------------------------------------------------------------
// prep: weight repack (one 32x32 tile unit per block) + biasCat.
// ---------------------------------------------------------------------------
__global__ __launch_bounds__(256) void prep_kernel(
    const float* __restrict__ bmu, const float* __restrict__ blv,
    float* __restrict__ biasCat, WTab tab)
{
    const int tid = threadIdx.x, bid = blockIdx.x;
    if (bid == 0 && tid < 64)
        biasCat[tid] = (tid < 32) ? bmu[tid] : blv[tid - 32];

    __shared__ float tbuf[32][33];
    int i = 0;
    while (i < 9 && bid >= tab.e[i + 1].cum) ++i;
    const WEnt en = tab.e[i];
    const int t = bid - en.cum;
    const int perE = en.Ksteps * en.Mtiles;
    const int e = t / perE;
    const int rr = t - e * perE;
    const int mt = rr / en.Ksteps;
    const int ks = rr - mt * en.Ksteps;
    const int tx = tid & 31, ty = tid >> 5;
    const float* src = en.src + (size_t)e * en.K * en.M;
    #pragma unroll
    for (int i0 = 0; i0 < 32; i0 += 8) {
        const int k = ks * 32 + i0 + ty, m = mt * 32 + tx;
        tbuf[i0 + ty][tx] = (k < en.K && m < en.M) ? src[(size_t)k * en.M + m] : 0.f;
    }
    __syncthreads();
    bf16* dst = en.dst + ((size_t)(e * en.Ksteps + ks) * en.Mtot + en.mOff + mt * 32) * 32;
    #pragma unroll
    for (int i0 = 0; i0 < 32; i0 += 8)
        dst[(size_t)(i0 + ty) * 32 + tx] = __float2bfloat16(tbuf[tx][i0 + ty]);
}

// ---------------------------------------------------------------------------
// fused: the ENTIRE network for 16 rows per block. 256 blocks = 1/CU.
// 1024 threads = 16 waves (4/SIMD). __launch_bounds__(1024,4): one block is
// already 4 waves/SIMD, so this targets exactly that residency -> 128-VGPR
// cap (R4's (1024,2) was compiled to a 64-VGPR cap: av[10]+6 accumulators
// didn't fit, forcing LDS re-reads and prefetch depth ~2 -> latency-bound).
// Gate chain runs barrier-free on wave 0 (all stages wave-internal),
// overlapped with expert partials on all waves. Every K-chain is split into
// two accumulators for MFMA/load ILP.
// ---------------------------------------------------------------------------
__global__ __launch_bounds__(1024, 4) void fused_kernel(
    const float* __restrict__ x, const float* __restrict__ c,
    const float* __restrict__ eps,
    const bf16* __restrict__ We1, const float* __restrict__ eb1,
    const bf16* __restrict__ We2, const float* __restrict__ eb2,
    const bf16* __restrict__ Wml, const float* __restrict__ biasCat,
    const bf16* __restrict__ Wg0, const float* __restrict__ gb0,
    const bf16* __restrict__ Wg1, const float* __restrict__ gb1,
    const bf16* __restrict__ Wg2, const float* __restrict__ gb2,
    const bf16* __restrict__ W0, const float* __restrict__ b0,
    const bf16* __restrict__ W1, const float* __restrict__ b1,
    const bf16* __restrict__ W2, const float* __restrict__ b2,
    float* __restrict__ out_layer, float* __restrict__ out_mu,
    float* __restrict__ out_lv)
{
    __shared__ bf16  bufA[16 * 552];
    __shared__ bf16  bufB[16 * 552];
    __shared__ float sML[16 * 64];
    __shared__ bf16  sG1[16 * 72];
    __shared__ bf16  sG2[16 * 72];
    __shared__ float sLg[16 * 16];
    __shared__ float sCo[EXPERTS * 16];

    const int tid  = threadIdx.x;
    const int w    = tid >> 6, lane = tid & 63, ml = lane & 15, quad = lane >> 4;
    const int row0 = blockIdx.x * 16;

    // ---- Ph0: bufA = [x|c] bf16 (Kpad 544, zero 534..543). row = w. ----
    {
        const float* xr = x + (size_t)(row0 + w) * FRAME;
        const float* cr = c + (size_t)(row0 + w) * FRAME;
        #pragma unroll
        for (int j = 0; j < 9; ++j) {
            const int col = lane + j * 64;
            if (col < 544) {
                float v = 0.f;
                if (col < FRAME)          v = xr[col];
                else if (col < 2 * FRAME) v = cr[col - FRAME];
                bufA[w * 552 + col] = __float2bfloat16(v);
            }
        }
    }
    __syncthreads();

    // ---- Ph1: h1 = elu([x|c] @ We1 + eb1), M=256 (16 tiles); bufB=[x|h1] ----
    {
        const int col = 16 * w + ml;
        f32x4 pa = (f32x4){0,0,0,0}, pb = (f32x4){0,0,0,0};
        const bf16* wp = We1 + (size_t)col * 32 + quad * 8;
        #pragma unroll
        for (int ks = 0; ks < 16; ks += 2) {
            const bf16x8 a0 = *(const bf16x8*)(bufA + ml * 552 + ks * 32 + quad * 8);
            const bf16x8 a1 = *(const bf16x8*)(bufA + ml * 552 + (ks + 1) * 32 + quad * 8);
            pa = MFMA(a0, *(const bf16x8*)(wp + (size_t)ks * 256 * 32), pa);
            pb = MFMA(a1, *(const bf16x8*)(wp + (size_t)(ks + 1) * 256 * 32), pb);
        }
        {
            const bf16x8 a16 = *(const bf16x8*)(bufA + ml * 552 + 16 * 32 + quad * 8);
            pa = MFMA(a16, *(const bf16x8*)(wp + (size_t)16 * 256 * 32), pa);
        }
        const float bv = eb1[col];
        #pragma unroll
        for (int rg = 0; rg < 4; ++rg)
            bufB[(quad * 4 + rg) * 552 + 267 + col] =
                __float2bfloat16(eluf(pa[rg] + pb[rg] + bv));
        // copy x -> bufB[0..266] (row w); zero pad 523..543
        #pragma unroll
        for (int j = 0; j < 5; ++j) {
            const int cc = lane + j * 64;
            if (cc < 267) bufB[w * 552 + cc] = bufA[w * 552 + cc];
        }
        if (lane < 21) bufB[w * 552 + 523 + lane] = __float2bfloat16(0.f);
    }
    __syncthreads();

    // ---- Ph2: h2 = elu([x|h1] @ We2 + eb2) -> bufB in-place = [x|h2] ----
    {
        const int col = 16 * w + ml;
        f32x4 pa = (f32x4){0,0,0,0}, pb = (f32x4){0,0,0,0};
        const bf16* wp = We2 + (size_t)col * 32 + quad * 8;
        #pragma unroll
        for (int ks = 0; ks < 16; ks += 2) {
            const bf16x8 a0 = *(const bf16x8*)(bufB + ml * 552 + ks * 32 + quad * 8);
            const bf16x8 a1 = *(const bf16x8*)(bufB + ml * 552 + (ks + 1) * 32 + quad * 8);
            pa = MFMA(a0, *(const bf16x8*)(wp + (size_t)ks * 256 * 32), pa);
            pb = MFMA(a1, *(const bf16x8*)(wp + (size_t)(ks + 1) * 256 * 32), pb);
        }
        {
            const bf16x8 a16 = *(const bf16x8*)(bufB + ml * 552 + 16 * 32 + quad * 8);
            pa = MFMA(a16, *(const bf16x8*)(wp + (size_t)16 * 256 * 32), pa);
        }
        __syncthreads();   // all reads of bufB done before overwrite
        const float bv = eb2[col];
        #pragma unroll
        for (int rg = 0; rg < 4; ++rg)
            bufB[(quad * 4 + rg) * 552 + 267 + col] =
                __float2bfloat16(eluf(pa[rg] + pb[rg] + bv));
    }
    __syncthreads();

    // ---- Ph3: mu|lv = [x|h2] @ Wml + biasCat (M=64, waves 0..3) ----
    if (w < 4) {
        const int col = 16 * w + ml;
        f32x4 pa = (f32x4){0,0,0,0}, pb = (f32x4){0,0,0,0};
        const bf16* wp = Wml + (size_t)col * 32 + quad * 8;
        #pragma unroll
        for (int ks = 0; ks < 16; ks += 2) {
            const bf16x8 a0 = *(const bf16x8*)(bufB + ml * 552 + ks * 32 + quad * 8);
            const bf16x8 a1 = *(const bf16x8*)(bufB + ml * 552 + (ks + 1) * 32 + quad * 8);
            pa = MFMA(a0, *(const bf16x8*)(wp + (size_t)ks * 64 * 32), pa);
            pb = MFMA(a1, *(const bf16x8*)(wp + (size_t)(ks + 1) * 64 * 32), pb);
        }
        {
            const bf16x8 a16 = *(const bf16x8*)(bufB + ml * 552 + 16 * 32 + quad * 8);
            pa = MFMA(a16, *(const bf16x8*)(wp + (size_t)16 * 64 * 32), pa);
        }
        const float bv = biasCat[col];
        #pragma unroll
        for (int rg = 0; rg < 4; ++rg)
            sML[(quad * 4 + rg) * 64 + col] = pa[rg] + pb[rg] + bv;
    }
    __syncthreads();

    // ---- Ph3b: z; bufB = [z|c] (Kpad 320); bufA[0..31] = z ----
    if (tid < 512) {
        const int r = tid >> 5, l = tid & 31;
        const float m  = sML[r * 64 + l];
        const float lv = sML[r * 64 + 32 + l];
        const int gi = (row0 + r) * LATENT + l;
        out_mu[gi] = m; out_lv[gi] = lv;
        const bf16 zb = __float2bfloat16(m + eps[gi] * expf(0.5f * lv));
        bufA[r * 552 + l] = zb;       // prefix of [z|dh1]
        bufB[r * 552 + l] = zb;       // prefix of [z|c]
        #pragma unroll
        for (int j = 0; j < 9; ++j) {
            const int col = 32 + l + j * 32;          // 32..319
            bf16 v = __float2bfloat16(0.f);
            if (col < 299) v = bufA[r * 552 + 267 + (col - 32)];   // c
            bufB[r * 552 + col] = v;
        }
    }
    __syncthreads();

    // ---- Ph5: gate (wave 0, barrier-free) overlapped with expert partials
    //      (all 16 waves, deferred blend); one barrier; blend -> bufA=[z|dh1]
    {
        const int col = 16 * w + ml;
        bf16x8 av[10];
        #pragma unroll
        for (int ks = 0; ks < 10; ++ks)
            av[ks] = *(const bf16x8*)(bufB + ml * 552 + ks * 32 + quad * 8);

        if (w == 0) {
            // g1: M=64 (4 tiles), K=320 (10 ksteps). A-fragments == av.
            #pragma unroll
            for (int t = 0; t < 4; ++t) {
                const int gc = 16 * t + ml;
                f32x4 p = (f32x4){0,0,0,0};
                const bf16* wp = Wg0 + (size_t)gc * 32 + quad * 8;
                #pragma unroll
                for (int ks = 0; ks < 10; ++ks)
                    p = MFMA(av[ks], *(const bf16x8*)(wp + (size_t)ks * 64 * 32), p);
                const float bv = gb0[gc];
                #pragma unroll
                for (int rg = 0; rg < 4; ++rg)
                    sG1[(quad * 4 + rg) * 72 + gc] = __float2bfloat16(eluf(p[rg] + bv));
            }
            // g2: M=64 (4 tiles), K=64 (2 ksteps) — same-wave LDS dep (lgkmcnt)
            #pragma unroll
            for (int t = 0; t < 4; ++t) {
                const int gc = 16 * t + ml;
                f32x4 p = (f32x4){0,0,0,0};
                const bf16* wp = Wg1 + (size_t)gc * 32 + quad * 8;
                #pragma unroll
                for (int ks = 0; ks < 2; ++ks)
                    p = MFMA(*(const bf16x8*)(sG1 + ml * 72 + ks * 32 + quad * 8),
                             *(const bf16x8*)(wp + (size_t)ks * 64 * 32), p);
                const float bv = gb1[gc];
                #pragma unroll
                for (int rg = 0; rg < 4; ++rg)
                    sG2[(quad * 4 + rg) * 72 + gc] = __float2bfloat16(eluf(p[rg] + bv));
            }
            // logits: M=6 (Mtot 32)
            {
                f32x4 p = (f32x4){0,0,0,0};
                const bf16* wp = Wg2 + (size_t)ml * 32 + quad * 8;
                #pragma unroll
                for (int ks = 0; ks < 2; ++ks)
                    p = MFMA(*(const bf16x8*)(sG2 + ml * 72 + ks * 32 + quad * 8),
                             *(const bf16x8*)(wp + (size_t)ks * 32 * 32), p);
                const float bv = (ml < EXPERTS) ? gb2[ml] : 0.f;
                #pragma unroll
                for (int rg = 0; rg < 4; ++rg)
                    sLg[(quad * 4 + rg) * 16 + ml] = p[rg] + bv;
            }
            // softmax on lanes 0-15 (same wave -> sLg visible via lgkmcnt)
            if (lane < 16) {
                float v[EXPERTS];
                float m = -1e30f;
                #pragma unroll
                for (int i = 0; i < EXPERTS; ++i) { v[i] = sLg[lane * 16 + i]; m = fmaxf(m, v[i]); }
                float s = 0.f;
                #pragma unroll
                for (int i = 0; i < EXPERTS; ++i) { v[i] = expf(v[i] - m); s += v[i]; }
                const float inv = 1.f / s;
                #pragma unroll
                for (int i = 0; i < EXPERTS; ++i) sCo[i * 16 + lane] = v[i] * inv;
            }
        }

        // expert partials (all waves), two chains per expert for ILP
        f32x4 pe0, pe1, pe2, pe3, pe4, pe5;
        auto moe_part = [&](int e, f32x4& pe) {
            const bf16* wp = W0 + ((size_t)e * 10 * 256 + col) * 32 + quad * 8;
            f32x4 pa = (f32x4){0,0,0,0}, pb = (f32x4){0,0,0,0};
            #pragma unroll
            for (int ks = 0; ks < 10; ks += 2) {
                pa = MFMA(av[ks],     *(const bf16x8*)(wp + (size_t)ks * 256 * 32), pa);
                pb = MFMA(av[ks + 1], *(const bf16x8*)(wp + (size_t)(ks + 1) * 256 * 32), pb);
            }
            pe = pa + pb;
        };
        moe_part(0, pe0); moe_part(1, pe1); moe_part(2, pe2);
        moe_part(3, pe3); moe_part(4, pe4); moe_part(5, pe5);
        __syncthreads();   // sCo ready + all partials done

        f32x4 acc = (f32x4){0,0,0,0};
        auto blend = [&](const f32x4& p, int e) {
            const float bv = b0[e * 256 + col];
            #pragma unroll
            for (int rg = 0; rg < 4; ++rg)
                acc[rg] += sCo[e * 16 + quad * 4 + rg] * (p[rg] + bv);
        };
        blend(pe0, 0); blend(pe1, 1); blend(pe2, 2);
        blend(pe3, 3); blend(pe4, 4); blend(pe5, 5);
        #pragma unroll
        for (int rg = 0; rg < 4; ++rg)
            bufA[(quad * 4 + rg) * 552 + 32 + col] = __float2bfloat16(eluf(acc[rg]));
    }
    __syncthreads();

    // ---- Ph6: dh2 = elu(moe([z|dh1], W1, b1)), M=256 -> bufB = [z|dh2] ----
    {
        const int col = 16 * w + ml;
        bf16x8 av[9];
        #pragma unroll
        for (int ks = 0; ks < 9; ++ks)
            av[ks] = *(const bf16x8*)(bufA + ml * 552 + ks * 32 + quad * 8);
        f32x4 acc = (f32x4){0,0,0,0};
        #pragma unroll
        for (int e = 0; e < EXPERTS; ++e) {
            const bf16* wp = W1 + ((size_t)e * 9 * 256 + col) * 32 + quad * 8;
            f32x4 pa = (f32x4){0,0,0,0}, pb = (f32x4){0,0,0,0};
            #pragma unroll
            for (int ks = 0; ks < 8; ks += 2) {
                pa = MFMA(av[ks],     *(const bf16x8*)(wp + (size_t)ks * 256 * 32), pa);
                pb = MFMA(av[ks + 1], *(const bf16x8*)(wp + (size_t)(ks + 1) * 256 * 32), pb);
            }
            pa = MFMA(av[8], *(const bf16x8*)(wp + (size_t)8 * 256 * 32), pa);
            const float bv = b1[e * 256 + col];
            #pragma unroll
            for (int rg = 0; rg < 4; ++rg)
                acc[rg] += sCo[e * 16 + quad * 4 + rg] * (pa[rg] + pb[rg] + bv);
        }
        // writes go to bufB; last bufB reads were before the Ph5-end barrier
        #pragma unroll
        for (int rg = 0; rg < 4; ++rg)
            bufB[(quad * 4 + rg) * 552 + 32 + col] = __float2bfloat16(eluf(acc[rg]));
    }
    __syncthreads();

    // ---- Ph7: out = moe([z|dh2], W2, b2), M=267 (18 tiles) -> global ----
    {
        bf16x8 av[9];
        #pragma unroll
        for (int ks = 0; ks < 9; ++ks)
            av[ks] = *(const bf16x8*)(bufB + ml * 552 + ks * 32 + quad * 8);
        for (int t = w; t < 18; t += 16) {
            const int col = 16 * t + ml;
            f32x4 acc = (f32x4){0,0,0,0};
            #pragma unroll
            for (int e = 0; e < EXPERTS; ++e) {
                const bf16* wp = W2 + ((size_t)e * 9 * 320 + col) * 32 + quad * 8;
                f32x4 pa = (f32x4){0,0,0,0}, pb = (f32x4){0,0,0,0};
                #pragma unroll
                for (int ks = 0; ks < 8; ks += 2) {
                    pa = MFMA(av[ks],     *(const bf16x8*)(wp + (size_t)ks * 320 * 32), pa);
                    pb = MFMA(av[ks + 1], *(const bf16x8*)(wp + (size_t)(ks + 1) * 320 * 32), pb);
                }
                pa = MFMA(av[8], *(const bf16x8*)(wp + (size_t)8 * 320 * 32), pa);
                const float bv = (col < FRAME) ? b2[e * FRAME + col] : 0.f;
                #pragma unroll
                for (int rg = 0; rg < 4; ++rg)
                    acc[rg] += sCo[e * 16 + quad * 4 + rg] * (pa[rg] + pb[rg] + bv);
            }
            if (col < FRAME) {
                #pragma unroll
                for (int rg = 0; rg < 4; ++rg)
                    out_layer[(size_t)(row0 + quad * 4 + rg) * FRAME + col] = acc[rg];
            }
        }
    }
}

// ---------------------------------------------------------------------------
extern "C" void kernel_launch(void* const* d_in, const int* in_sizes, int n_in,
                              void* d_out, int out_size, void* d_ws, size_t ws_size,
                              hipStream_t stream) {
    const float* x       = (const float*)d_in[0];
    const float* c       = (const float*)d_in[1];
    const float* eps     = (const float*)d_in[2];
    const float* enc_w1  = (const float*)d_in[3];
    const float* enc_b1  = (const float*)d_in[4];
    const float* enc_w2  = (const float*)d_in[5];
    const float* enc_b2  = (const float*)d_in[6];
    const float* enc_wmu = (const float*)d_in[7];
    const float* enc_bmu = (const float*)d_in[8];
    const float* enc_wlv = (const float*)d_in[9];
    const float* enc_blv = (const float*)d_in[10];
    const float* g_w0    = (const float*)d_in[11];
    const float* g_b0    = (const float*)d_in[12];
    const float* g_w1    = (const float*)d_in[13];
    const float* g_b1    = (const float*)d_in[14];
    const float* g_w2    = (const float*)d_in[15];
    const float* g_b2    = (const float*)d_in[16];
    const float* w0      = (const float*)d_in[17];
    const float* b0      = (const float*)d_in[18];
    const float* w1      = (const float*)d_in[19];
    const float* b1      = (const float*)d_in[20];
    const float* w2      = (const float*)d_in[21];
    const float* b2      = (const float*)d_in[22];

    // output (f32): [layer (4096x267) | mu (4096x32) | logvar (4096x32)]
    float* out_layer = (float*)d_out;
    float* out_mu    = out_layer + (size_t)N_BATCH * FRAME;
    float* out_lv    = out_mu    + (size_t)N_BATCH * LATENT;

    // ---- workspace layout (16B-aligned): biasCat + repacked weights only ----
    char* p = (char*)d_ws;
    float* biasCat = (float*)p;  p += 64 * 4;
    bf16* Wt_e1 = (bf16*)p;      p += (size_t)17 * 256 * 32 * 2;
    bf16* Wt_e2 = (bf16*)p;      p += (size_t)17 * 256 * 32 * 2;
    bf16* Wt_ml = (bf16*)p;      p += (size_t)17 * 64 * 32 * 2;
    bf16* Wt_g0 = (bf16*)p;      p += (size_t)10 * 64 * 32 * 2;
    bf16* Wt_g1 = (bf16*)p;      p += (size_t)2 * 64 * 32 * 2;
    bf16* Wt_g2 = (bf16*)p;      p += (size_t)2 * 32 * 32 * 2;
    bf16* Wt_w0 = (bf16*)p;      p += (size_t)EXPERTS * 10 * 256 * 32 * 2;
    bf16* Wt_w1 = (bf16*)p;      p += (size_t)EXPERTS * 9 * 256 * 32 * 2;
    bf16* Wt_w2 = (bf16*)p;      p += (size_t)EXPERTS * 9 * 320 * 32 * 2;

    WTab tab;
    int cum = 0, n = 0;
    auto add = [&](const float* src, bf16* dst, int K, int M, int Mtot, int mOff, int E) {
        int Ksteps;
        if (K == 534 || K == 523) Ksteps = 17;
        else if (K == 299) Ksteps = 10;
        else if (K == 288) Ksteps = 9;
        else Ksteps = 2;   // K=64
        const int Mtiles = (M + 31) / 32;
        tab.e[n] = {src, dst, K, M, Mtot, mOff, Ksteps, Mtiles, cum};
        cum += E * Ksteps * Mtiles;
        ++n;
    };
    add(enc_w1,  Wt_e1, 534, 256, 256, 0, 1);
    add(enc_w2,  Wt_e2, 523, 256, 256, 0, 1);
    add(enc_wmu, Wt_ml, 523, 32, 64, 0, 1);
    add(enc_wlv, Wt_ml, 523, 32, 64, 32, 1);
    add(g_w0,    Wt_g0, 299, 64, 64, 0, 1);
    add(g_w1,    Wt_g1, 64, 64, 64, 0, 1);
    add(g_w2,    Wt_g2, 64, 6, 32, 0, 1);
    add(w0,      Wt_w0, 299, 256, 256, 0, EXPERTS);
    add(w1,      Wt_w1, 288, 256, 256, 0, EXPERTS);
    add(w2,      Wt_w2, 288, 267, 320, 0, EXPERTS);
    tab.total = cum;

    // 0) prep: weight repack (cum blocks) + biasCat
    prep_kernel<<<dim3(cum), dim3(256), 0, stream>>>(enc_bmu, enc_blv, biasCat, tab);

    // 1) fully fused network: 256 blocks x 1024 threads (1 block/CU, 16 waves)
    fused_kernel<<<dim3(N_BATCH / 16), dim3(1024), 0, stream>>>(
        x, c, eps,
        Wt_e1, enc_b1, Wt_e2, enc_b2, Wt_ml, biasCat,
        Wt_g0, g_b0, Wt_g1, g_b1, Wt_g2, g_b2,
        Wt_w0, b0, Wt_w1, b1, Wt_w2, b2,
        out_layer, out_mu, out_lv);
}

// Round 7
// 166.928 us; speedup vs baseline: 1.0663x; 1.0663x over previous
//
#include <hip/hip_runtime.h>
#include <hip/hip_bf16.h>
#include <math.h>

// Problem constants (PoseMixtureVAE)
#define N_BATCH 4096
#define FRAME   267
#define LATENT  32
#define HIDDEN  256
#define GATE_H  64
#define EXPERTS 6
// Kpads: [x|c]=534->544 (17 ksteps), [x|h]=523->544 (17), [z|c]=299->320 (10),
//        [z|h]=288 (9 exactly), gate hidden 64 (2)

typedef __hip_bfloat16 bf16;
typedef __bf16  bf16x8 __attribute__((ext_vector_type(8)));
typedef float   f32x4  __attribute__((ext_vector_type(4)));

__device__ __forceinline__ float eluf(float v) { return (v > 0.f) ? v : (expf(v) - 1.f); }

#define MFMA(a, b, p) __builtin_amdgcn_mfma_f32_16x16x32_bf16((a), (b), (p), 0, 0, 0)

struct WEnt { const float* src; bf16* dst; int K, M, Mtot, mOff, Ksteps, Mtiles, cum; };
struct WTab { WEnt e[10]; int total; };

// ---------------------------------------------------------------------------
// prep: weight repack (one 32x32 tile unit per block) + biasCat.
// ---------------------------------------------------------------------------
__global__ __launch_bounds__(256) void prep_kernel(
    const float* __restrict__ bmu, const float* __restrict__ blv,
    float* __restrict__ biasCat, WTab tab)
{
    const int tid = threadIdx.x, bid = blockIdx.x;
    if (bid == 0 && tid < 64)
        biasCat[tid] = (tid < 32) ? bmu[tid] : blv[tid - 32];

    __shared__ float tbuf[32][33];
    int i = 0;
    while (i < 9 && bid >= tab.e[i + 1].cum) ++i;
    const WEnt en = tab.e[i];
    const int t = bid - en.cum;
    const int perE = en.Ksteps * en.Mtiles;
    const int e = t / perE;
    const int rr = t - e * perE;
    const int mt = rr / en.Ksteps;
    const int ks = rr - mt * en.Ksteps;
    const int tx = tid & 31, ty = tid >> 5;
    const float* src = en.src + (size_t)e * en.K * en.M;
    #pragma unroll
    for (int i0 = 0; i0 < 32; i0 += 8) {
        const int k = ks * 32 + i0 + ty, m = mt * 32 + tx;
        tbuf[i0 + ty][tx] = (k < en.K && m < en.M) ? src[(size_t)k * en.M + m] : 0.f;
    }
    __syncthreads();
    bf16* dst = en.dst + ((size_t)(e * en.Ksteps + ks) * en.Mtot + en.mOff + mt * 32) * 32;
    #pragma unroll
    for (int i0 = 0; i0 < 32; i0 += 8)
        dst[(size_t)(i0 + ty) * 32 + tx] = __float2bfloat16(tbuf[tx][i0 + ty]);
}

// ---------------------------------------------------------------------------
// fused: the ENTIRE network for 16 rows per block. 256 blocks = 1/CU.
// 1024 threads = 16 waves (4/SIMD). Unified VGPR+AGPR budget at this block
// size is 128/wave (hard cap) — so: A-fragments are read from LDS per MFMA
// (no av[] hoist), and the freed registers hold an explicit 8-deep register
// double-buffer for the B-stream (ring bb[.] with compile-time indices).
// NOTE: ring alignment — the fill bb[j]=W[base+j] pairs with consumption
// bb[v&7] where v counts FROM 0 (R6 bug: consumed bb[u&7] with u from 30).
// ---------------------------------------------------------------------------
__global__ __launch_bounds__(1024, 4) void fused_kernel(
    const float* __restrict__ x, const float* __restrict__ c,
    const float* __restrict__ eps,
    const bf16* __restrict__ We1, const float* __restrict__ eb1,
    const bf16* __restrict__ We2, const float* __restrict__ eb2,
    const bf16* __restrict__ Wml, const float* __restrict__ biasCat,
    const bf16* __restrict__ Wg0, const float* __restrict__ gb0,
    const bf16* __restrict__ Wg1, const float* __restrict__ gb1,
    const bf16* __restrict__ Wg2, const float* __restrict__ gb2,
    const bf16* __restrict__ W0, const float* __restrict__ b0,
    const bf16* __restrict__ W1, const float* __restrict__ b1,
    const bf16* __restrict__ W2, const float* __restrict__ b2,
    float* __restrict__ out_layer, float* __restrict__ out_mu,
    float* __restrict__ out_lv)
{
    __shared__ bf16  bufA[16 * 552];
    __shared__ bf16  bufB[16 * 552];
    __shared__ float sMLp[4][16 * 64];
    __shared__ bf16  sG1[16 * 72];
    __shared__ bf16  sG2[16 * 72];
    __shared__ float sLg[16 * 16];
    __shared__ float sCo[EXPERTS * 16];

    const int tid  = threadIdx.x;
    const int w    = tid >> 6, lane = tid & 63, ml = lane & 15, quad = lane >> 4;
    const int row0 = blockIdx.x * 16;

    // ---- Ph0: bufA = [x|c] bf16 (Kpad 544, zero 534..543). row = w. ----
    {
        const float* xr = x + (size_t)(row0 + w) * FRAME;
        const float* cr = c + (size_t)(row0 + w) * FRAME;
        #pragma unroll
        for (int j = 0; j < 9; ++j) {
            const int col = lane + j * 64;
            if (col < 544) {
                float v = 0.f;
                if (col < FRAME)          v = xr[col];
                else if (col < 2 * FRAME) v = cr[col - FRAME];
                bufA[w * 552 + col] = __float2bfloat16(v);
            }
        }
    }
    __syncthreads();

    // ---- Ph1: h1 = elu([x|c] @ We1 + eb1), M=256 (16 tiles); bufB=[x|h1] ----
    {
        const int col = 16 * w + ml;
        const bf16* wq = We1 + (size_t)col * 32 + quad * 8;   // u-stride 8192
        f32x4 acc = (f32x4){0,0,0,0};
        bf16x8 bb[8];
        #pragma unroll
        for (int j = 0; j < 8; ++j) bb[j] = *(const bf16x8*)(wq + (size_t)j * 8192);
        #pragma unroll
        for (int u = 0; u < 17; ++u) {
            const bf16x8 b = bb[u & 7];
            if (u + 8 < 17) bb[u & 7] = *(const bf16x8*)(wq + (size_t)(u + 8) * 8192);
            acc = MFMA(*(const bf16x8*)(bufA + ml * 552 + u * 32 + quad * 8), b, acc);
        }
        const float bv = eb1[col];
        #pragma unroll
        for (int rg = 0; rg < 4; ++rg)
            bufB[(quad * 4 + rg) * 552 + 267 + col] = __float2bfloat16(eluf(acc[rg] + bv));
        // copy x -> bufB[0..266] (row w); zero pad 523..543
        #pragma unroll
        for (int j = 0; j < 5; ++j) {
            const int cc = lane + j * 64;
            if (cc < 267) bufB[w * 552 + cc] = bufA[w * 552 + cc];
        }
        if (lane < 21) bufB[w * 552 + 523 + lane] = __float2bfloat16(0.f);
    }
    __syncthreads();

    // ---- Ph2: h2 = elu([x|h1] @ We2 + eb2) -> bufB in-place = [x|h2] ----
    {
        const int col = 16 * w + ml;
        const bf16* wq = We2 + (size_t)col * 32 + quad * 8;
        f32x4 acc = (f32x4){0,0,0,0};
        bf16x8 bb[8];
        #pragma unroll
        for (int j = 0; j < 8; ++j) bb[j] = *(const bf16x8*)(wq + (size_t)j * 8192);
        #pragma unroll
        for (int u = 0; u < 17; ++u) {
            const bf16x8 b = bb[u & 7];
            if (u + 8 < 17) bb[u & 7] = *(const bf16x8*)(wq + (size_t)(u + 8) * 8192);
            acc = MFMA(*(const bf16x8*)(bufB + ml * 552 + u * 32 + quad * 8), b, acc);
        }
        __syncthreads();   // all reads of bufB done before overwrite
        const float bv = eb2[col];
        #pragma unroll
        for (int rg = 0; rg < 4; ++rg)
            bufB[(quad * 4 + rg) * 552 + 267 + col] = __float2bfloat16(eluf(acc[rg] + bv));
    }
    __syncthreads();

    // ---- Ph3: mu|lv partial-K: wave w -> col tile (w&3), k-group (w>>2) ----
    {
        const int t = w & 3, kg = w >> 2;
        const int col = 16 * t + ml;
        const int k0 = kg * 4, k1 = (kg == 3) ? 17 : kg * 4 + 4;
        const bf16* wq = Wml + (size_t)col * 32 + quad * 8;   // u-stride 2048
        f32x4 p = (f32x4){0,0,0,0};
        #pragma unroll
        for (int u = 0; u < 5; ++u) {
            const int ks = k0 + u;
            if (ks < k1)
                p = MFMA(*(const bf16x8*)(bufB + ml * 552 + ks * 32 + quad * 8),
                         *(const bf16x8*)(wq + (size_t)ks * 2048), p);
        }
        #pragma unroll
        for (int rg = 0; rg < 4; ++rg)
            sMLp[kg][(quad * 4 + rg) * 64 + col] = p[rg];
    }
    __syncthreads();

    // ---- Ph3b: z; bufB = [z|c] (Kpad 320); bufA[0..31] = z ----
    if (tid < 512) {
        const int r = tid >> 5, l = tid & 31;
        const float m  = sMLp[0][r * 64 + l] + sMLp[1][r * 64 + l]
                       + sMLp[2][r * 64 + l] + sMLp[3][r * 64 + l] + biasCat[l];
        const float lv = sMLp[0][r * 64 + 32 + l] + sMLp[1][r * 64 + 32 + l]
                       + sMLp[2][r * 64 + 32 + l] + sMLp[3][r * 64 + 32 + l] + biasCat[32 + l];
        const int gi = (row0 + r) * LATENT + l;
        out_mu[gi] = m; out_lv[gi] = lv;
        const bf16 zb = __float2bfloat16(m + eps[gi] * expf(0.5f * lv));
        bufA[r * 552 + l] = zb;       // prefix of [z|dh1]
        bufB[r * 552 + l] = zb;       // prefix of [z|c]
        #pragma unroll
        for (int j = 0; j < 9; ++j) {
            const int col = 32 + l + j * 32;          // 32..319
            bf16 v = __float2bfloat16(0.f);
            if (col < 299) v = bufA[r * 552 + 267 + (col - 32)];   // c
            bufB[r * 552 + col] = v;
        }
    }
    __syncthreads();

    // ---- Ph5: MoE layer 0 (experts split 0-2 / 3-5) overlapped with gate ----
    {
        const int col = 16 * w + ml;
        const bf16* wq = W0 + (size_t)col * 32 + quad * 8;    // u = e*10+ks, stride 8192
        f32x4 pe[6] = {(f32x4){0,0,0,0}, (f32x4){0,0,0,0}, (f32x4){0,0,0,0},
                       (f32x4){0,0,0,0}, (f32x4){0,0,0,0}, (f32x4){0,0,0,0}};

        // chunk A: gate g1 (waves 0-3) + experts 0-2 (all waves), u = 0..29
        if (w < 4) {
            const int gc = 16 * w + ml;
            const bf16* gq = Wg0 + (size_t)gc * 32 + quad * 8;   // stride 2048
            f32x4 p = (f32x4){0,0,0,0};
            #pragma unroll
            for (int ks = 0; ks < 10; ++ks)
                p = MFMA(*(const bf16x8*)(bufB + ml * 552 + ks * 32 + quad * 8),
                         *(const bf16x8*)(gq + (size_t)ks * 2048), p);
            const float bv = gb0[gc];
            #pragma unroll
            for (int rg = 0; rg < 4; ++rg)
                sG1[(quad * 4 + rg) * 72 + gc] = __float2bfloat16(eluf(p[rg] + bv));
        }
        {
            bf16x8 bb[8];
            #pragma unroll
            for (int j = 0; j < 8; ++j) bb[j] = *(const bf16x8*)(wq + (size_t)j * 8192);
            #pragma unroll
            for (int v = 0; v < 30; ++v) {
                const bf16x8 b = bb[v & 7];
                if (v + 8 < 30) bb[v & 7] = *(const bf16x8*)(wq + (size_t)(v + 8) * 8192);
                pe[v / 10] = MFMA(*(const bf16x8*)(bufB + ml * 552 + (v % 10) * 32 + quad * 8),
                                  b, pe[v / 10]);
            }
        }
        __syncthreads();

        // chunk B: gate g2+logits+softmax (wave 0) + experts 3-5, u = 30+v
        if (w == 0) {
            #pragma unroll
            for (int t = 0; t < 4; ++t) {
                const int gc = 16 * t + ml;
                const bf16* gq = Wg1 + (size_t)gc * 32 + quad * 8;
                f32x4 p = (f32x4){0,0,0,0};
                #pragma unroll
                for (int ks = 0; ks < 2; ++ks)
                    p = MFMA(*(const bf16x8*)(sG1 + ml * 72 + ks * 32 + quad * 8),
                             *(const bf16x8*)(gq + (size_t)ks * 2048), p);
                const float bv = gb1[gc];
                #pragma unroll
                for (int rg = 0; rg < 4; ++rg)
                    sG2[(quad * 4 + rg) * 72 + gc] = __float2bfloat16(eluf(p[rg] + bv));
            }
            {
                const bf16* gq = Wg2 + (size_t)ml * 32 + quad * 8;   // stride 1024
                f32x4 p = (f32x4){0,0,0,0};
                #pragma unroll
                for (int ks = 0; ks < 2; ++ks)
                    p = MFMA(*(const bf16x8*)(sG2 + ml * 72 + ks * 32 + quad * 8),
                             *(const bf16x8*)(gq + (size_t)ks * 1024), p);
                const float bv = (ml < EXPERTS) ? gb2[ml] : 0.f;
                #pragma unroll
                for (int rg = 0; rg < 4; ++rg)
                    sLg[(quad * 4 + rg) * 16 + ml] = p[rg] + bv;
            }
            if (lane < 16) {   // softmax (same wave -> sLg visible via lgkmcnt)
                float v[EXPERTS];
                float m = -1e30f;
                #pragma unroll
                for (int i = 0; i < EXPERTS; ++i) { v[i] = sLg[lane * 16 + i]; m = fmaxf(m, v[i]); }
                float s = 0.f;
                #pragma unroll
                for (int i = 0; i < EXPERTS; ++i) { v[i] = expf(v[i] - m); s += v[i]; }
                const float inv = 1.f / s;
                #pragma unroll
                for (int i = 0; i < EXPERTS; ++i) sCo[i * 16 + lane] = v[i] * inv;
            }
        }
        {
            bf16x8 bb[8];
            #pragma unroll
            for (int j = 0; j < 8; ++j) bb[j] = *(const bf16x8*)(wq + (size_t)(30 + j) * 8192);
            #pragma unroll
            for (int v = 0; v < 30; ++v) {          // u = 30 + v; ring indexed by v
                const bf16x8 b = bb[v & 7];
                if (v + 8 < 30) bb[v & 7] = *(const bf16x8*)(wq + (size_t)(30 + v + 8) * 8192);
                const int u = 30 + v;
                pe[u / 10] = MFMA(*(const bf16x8*)(bufB + ml * 552 + (u % 10) * 32 + quad * 8),
                                  b, pe[u / 10]);
            }
        }
        __syncthreads();   // sCo ready + all partials done

        f32x4 acc = (f32x4){0,0,0,0};
        #pragma unroll
        for (int e = 0; e < EXPERTS; ++e) {
            const float bv = b0[e * 256 + col];
            #pragma unroll
            for (int rg = 0; rg < 4; ++rg)
                acc[rg] += sCo[e * 16 + quad * 4 + rg] * (pe[e][rg] + bv);
        }
        #pragma unroll
        for (int rg = 0; rg < 4; ++rg)
            bufA[(quad * 4 + rg) * 552 + 32 + col] = __float2bfloat16(eluf(acc[rg]));
    }
    __syncthreads();

    // ---- Ph6: dh2 = elu(moe([z|dh1], W1, b1)), M=256 -> bufB = [z|dh2] ----
    {
        const int col = 16 * w + ml;
        const bf16* wq = W1 + (size_t)col * 32 + quad * 8;    // u = e*9+ks, stride 8192
        f32x4 pe[6] = {(f32x4){0,0,0,0}, (f32x4){0,0,0,0}, (f32x4){0,0,0,0},
                       (f32x4){0,0,0,0}, (f32x4){0,0,0,0}, (f32x4){0,0,0,0}};
        bf16x8 bb[8];
        #pragma unroll
        for (int j = 0; j < 8; ++j) bb[j] = *(const bf16x8*)(wq + (size_t)j * 8192);
        #pragma unroll
        for (int u = 0; u < 54; ++u) {
            const bf16x8 b = bb[u & 7];
            if (u + 8 < 54) bb[u & 7] = *(const bf16x8*)(wq + (size_t)(u + 8) * 8192);
            pe[u / 9] = MFMA(*(const bf16x8*)(bufA + ml * 552 + (u % 9) * 32 + quad * 8),
                             b, pe[u / 9]);
        }
        f32x4 acc = (f32x4){0,0,0,0};
        #pragma unroll
        for (int e = 0; e < EXPERTS; ++e) {
            const float bv = b1[e * 256 + col];
            #pragma unroll
            for (int rg = 0; rg < 4; ++rg)
                acc[rg] += sCo[e * 16 + quad * 4 + rg] * (pe[e][rg] + bv);
        }
        // writes to bufB; its last reads were before the Ph5-end barrier
        #pragma unroll
        for (int rg = 0; rg < 4; ++rg)
            bufB[(quad * 4 + rg) * 552 + 32 + col] = __float2bfloat16(eluf(acc[rg]));
    }
    __syncthreads();

    // ---- Ph7: out = moe([z|dh2], W2, b2), M=267 (17 tiles) -> global ----
    {
        for (int t = w; t < 17; t += 16) {
            const int col = 16 * t + ml;
            const bf16* wq = W2 + (size_t)col * 32 + quad * 8;   // stride 10240
            f32x4 pe[6] = {(f32x4){0,0,0,0}, (f32x4){0,0,0,0}, (f32x4){0,0,0,0},
                           (f32x4){0,0,0,0}, (f32x4){0,0,0,0}, (f32x4){0,0,0,0}};
            bf16x8 bb[8];
            #pragma unroll
            for (int j = 0; j < 8; ++j) bb[j] = *(const bf16x8*)(wq + (size_t)j * 10240);
            #pragma unroll
            for (int u = 0; u < 54; ++u) {
                const bf16x8 b = bb[u & 7];
                if (u + 8 < 54) bb[u & 7] = *(const bf16x8*)(wq + (size_t)(u + 8) * 10240);
                pe[u / 9] = MFMA(*(const bf16x8*)(bufB + ml * 552 + (u % 9) * 32 + quad * 8),
                                 b, pe[u / 9]);
            }
            f32x4 acc = (f32x4){0,0,0,0};
            #pragma unroll
            for (int e = 0; e < EXPERTS; ++e) {
                const float bv = (col < FRAME) ? b2[e * FRAME + col] : 0.f;
                #pragma unroll
                for (int rg = 0; rg < 4; ++rg)
                    acc[rg] += sCo[e * 16 + quad * 4 + rg] * (pe[e][rg] + bv);
            }
            if (col < FRAME) {
                #pragma unroll
                for (int rg = 0; rg < 4; ++rg)
                    out_layer[(size_t)(row0 + quad * 4 + rg) * FRAME + col] = acc[rg];
            }
        }
    }
}

// ---------------------------------------------------------------------------
extern "C" void kernel_launch(void* const* d_in, const int* in_sizes, int n_in,
                              void* d_out, int out_size, void* d_ws, size_t ws_size,
                              hipStream_t stream) {
    const float* x       = (const float*)d_in[0];
    const float* c       = (const float*)d_in[1];
    const float* eps     = (const float*)d_in[2];
    const float* enc_w1  = (const float*)d_in[3];
    const float* enc_b1  = (const float*)d_in[4];
    const float* enc_w2  = (const float*)d_in[5];
    const float* enc_b2  = (const float*)d_in[6];
    const float* enc_wmu = (const float*)d_in[7];
    const float* enc_bmu = (const float*)d_in[8];
    const float* enc_wlv = (const float*)d_in[9];
    const float* enc_blv = (const float*)d_in[10];
    const float* g_w0    = (const float*)d_in[11];
    const float* g_b0    = (const float*)d_in[12];
    const float* g_w1    = (const float*)d_in[13];
    const float* g_b1    = (const float*)d_in[14];
    const float* g_w2    = (const float*)d_in[15];
    const float* g_b2    = (const float*)d_in[16];
    const float* w0      = (const float*)d_in[17];
    const float* b0      = (const float*)d_in[18];
    const float* w1      = (const float*)d_in[19];
    const float* b1      = (const float*)d_in[20];
    const float* w2      = (const float*)d_in[21];
    const float* b2      = (const float*)d_in[22];

    // output (f32): [layer (4096x267) | mu (4096x32) | logvar (4096x32)]
    float* out_layer = (float*)d_out;
    float* out_mu    = out_layer + (size_t)N_BATCH * FRAME;
    float* out_lv    = out_mu    + (size_t)N_BATCH * LATENT;

    // ---- workspace layout (16B-aligned): biasCat + repacked weights only ----
    char* p = (char*)d_ws;
    float* biasCat = (float*)p;  p += 64 * 4;
    bf16* Wt_e1 = (bf16*)p;      p += (size_t)17 * 256 * 32 * 2;
    bf16* Wt_e2 = (bf16*)p;      p += (size_t)17 * 256 * 32 * 2;
    bf16* Wt_ml = (bf16*)p;      p += (size_t)17 * 64 * 32 * 2;
    bf16* Wt_g0 = (bf16*)p;      p += (size_t)10 * 64 * 32 * 2;
    bf16* Wt_g1 = (bf16*)p;      p += (size_t)2 * 64 * 32 * 2;
    bf16* Wt_g2 = (bf16*)p;      p += (size_t)2 * 32 * 32 * 2;
    bf16* Wt_w0 = (bf16*)p;      p += (size_t)EXPERTS * 10 * 256 * 32 * 2;
    bf16* Wt_w1 = (bf16*)p;      p += (size_t)EXPERTS * 9 * 256 * 32 * 2;
    bf16* Wt_w2 = (bf16*)p;      p += (size_t)EXPERTS * 9 * 320 * 32 * 2;

    WTab tab;
    int cum = 0, n = 0;
    auto add = [&](const float* src, bf16* dst, int K, int M, int Mtot, int mOff, int E) {
        int Ksteps;
        if (K == 534 || K == 523) Ksteps = 17;
        else if (K == 299) Ksteps = 10;
        else if (K == 288) Ksteps = 9;
        else Ksteps = 2;   // K=64
        const int Mtiles = (M + 31) / 32;
        tab.e[n] = {src, dst, K, M, Mtot, mOff, Ksteps, Mtiles, cum};
        cum += E * Ksteps * Mtiles;
        ++n;
    };
    add(enc_w1,  Wt_e1, 534, 256, 256, 0, 1);
    add(enc_w2,  Wt_e2, 523, 256, 256, 0, 1);
    add(enc_wmu, Wt_ml, 523, 32, 64, 0, 1);
    add(enc_wlv, Wt_ml, 523, 32, 64, 32, 1);
    add(g_w0,    Wt_g0, 299, 64, 64, 0, 1);
    add(g_w1,    Wt_g1, 64, 64, 64, 0, 1);
    add(g_w2,    Wt_g2, 64, 6, 32, 0, 1);
    add(w0,      Wt_w0, 299, 256, 256, 0, EXPERTS);
    add(w1,      Wt_w1, 288, 256, 256, 0, EXPERTS);
    add(w2,      Wt_w2, 288, 267, 320, 0, EXPERTS);
    tab.total = cum;

    // 0) prep: weight repack (cum blocks) + biasCat
    prep_kernel<<<dim3(cum), dim3(256), 0, stream>>>(enc_bmu, enc_blv, biasCat, tab);

    // 1) fully fused network: 256 blocks x 1024 threads (1 block/CU, 16 waves)
    fused_kernel<<<dim3(N_BATCH / 16), dim3(1024), 0, stream>>>(
        x, c, eps,
        Wt_e1, enc_b1, Wt_e2, enc_b2, Wt_ml, biasCat,
        Wt_g0, g_b0, Wt_g1, g_b1, Wt_g2, g_b2,
        Wt_w0, b0, Wt_w1, b1, Wt_w2, b2,
        out_layer, out_mu, out_lv);
}

// Round 8
// 166.553 us; speedup vs baseline: 1.0687x; 1.0023x over previous
//
#include <hip/hip_runtime.h>
#include <hip/hip_bf16.h>
#include <math.h>

// Problem constants (PoseMixtureVAE)
#define N_BATCH 4096
#define FRAME   267
#define LATENT  32
#define HIDDEN  256
#define GATE_H  64
#define EXPERTS 6
// Kpads: [x|c]=534->544 (17 ksteps), [x|h]=523->544 (17), [z|c]=299->320 (10),
//        [z|h]=288 (9 exactly), gate hidden 64 (2)

typedef __hip_bfloat16 bf16;
typedef __bf16  bf16x8 __attribute__((ext_vector_type(8)));
typedef float   f32x4  __attribute__((ext_vector_type(4)));

__device__ __forceinline__ float eluf(float v) { return (v > 0.f) ? v : (expf(v) - 1.f); }

#define MFMA(a, b, p) __builtin_amdgcn_mfma_f32_16x16x32_bf16((a), (b), (p), 0, 0, 0)

struct WEnt { const float* src; bf16* dst; int K, M, Mtot, mOff, Ksteps, Mtiles, cum; };
struct WTab { WEnt e[10]; int total; };

// ---------------------------------------------------------------------------
// prep: weight repack (one 32x32 tile unit per block) + biasCat.
// ---------------------------------------------------------------------------
__global__ __launch_bounds__(256) void prep_kernel(
    const float* __restrict__ bmu, const float* __restrict__ blv,
    float* __restrict__ biasCat, WTab tab)
{
    const int tid = threadIdx.x, bid = blockIdx.x;
    if (bid == 0 && tid < 64)
        biasCat[tid] = (tid < 32) ? bmu[tid] : blv[tid - 32];

    __shared__ float tbuf[32][33];
    int i = 0;
    while (i < 9 && bid >= tab.e[i + 1].cum) ++i;
    const WEnt en = tab.e[i];
    const int t = bid - en.cum;
    const int perE = en.Ksteps * en.Mtiles;
    const int e = t / perE;
    const int rr = t - e * perE;
    const int mt = rr / en.Ksteps;
    const int ks = rr - mt * en.Ksteps;
    const int tx = tid & 31, ty = tid >> 5;
    const float* src = en.src + (size_t)e * en.K * en.M;
    #pragma unroll
    for (int i0 = 0; i0 < 32; i0 += 8) {
        const int k = ks * 32 + i0 + ty, m = mt * 32 + tx;
        tbuf[i0 + ty][tx] = (k < en.K && m < en.M) ? src[(size_t)k * en.M + m] : 0.f;
    }
    __syncthreads();
    bf16* dst = en.dst + ((size_t)(e * en.Ksteps + ks) * en.Mtot + en.mOff + mt * 32) * 32;
    #pragma unroll
    for (int i0 = 0; i0 < 32; i0 += 8)
        dst[(size_t)(i0 + ty) * 32 + tx] = __float2bfloat16(tbuf[tx][i0 + ty]);
}

// ---------------------------------------------------------------------------
// fused: the ENTIRE network for 16 rows per block. 256 blocks = 1/CU.
// 1024 threads = 16 waves (4/SIMD). amdgpu_waves_per_eu(4,4): pin the
// compiler to 4 waves/EU so the allocator uses the full 128-VGPR budget
// (R7: launch_bounds alone -> compiler targeted 8/EU = 64 VGPR and
// serialized every B-load against its MFMA). B-stream is software-pipelined
// in named load-GROUPS (5-6 fragments), double-buffered: group g+1's loads
// are issued before group g's MFMAs consume their buffer.
// ---------------------------------------------------------------------------
__global__
__attribute__((amdgpu_flat_work_group_size(1024, 1024), amdgpu_waves_per_eu(4, 4)))
void fused_kernel(
    const float* __restrict__ x, const float* __restrict__ c,
    const float* __restrict__ eps,
    const bf16* __restrict__ We1, const float* __restrict__ eb1,
    const bf16* __restrict__ We2, const float* __restrict__ eb2,
    const bf16* __restrict__ Wml, const float* __restrict__ biasCat,
    const bf16* __restrict__ Wg0, const float* __restrict__ gb0,
    const bf16* __restrict__ Wg1, const float* __restrict__ gb1,
    const bf16* __restrict__ Wg2, const float* __restrict__ gb2,
    const bf16* __restrict__ W0, const float* __restrict__ b0,
    const bf16* __restrict__ W1, const float* __restrict__ b1,
    const bf16* __restrict__ W2, const float* __restrict__ b2,
    float* __restrict__ out_layer, float* __restrict__ out_mu,
    float* __restrict__ out_lv)
{
    __shared__ bf16  bufA[16 * 552];
    __shared__ bf16  bufB[16 * 552];
    __shared__ float sMLp[4][16 * 64];
    __shared__ bf16  sG1[16 * 72];
    __shared__ bf16  sG2[16 * 72];
    __shared__ float sLg[16 * 16];
    __shared__ float sCo[EXPERTS * 16];

    const int tid  = threadIdx.x;
    const int w    = tid >> 6, lane = tid & 63, ml = lane & 15, quad = lane >> 4;
    const int row0 = blockIdx.x * 16;

    // ---- Ph0: bufA = [x|c] bf16 (Kpad 544, zero 534..543). row = w. ----
    {
        const float* xr = x + (size_t)(row0 + w) * FRAME;
        const float* cr = c + (size_t)(row0 + w) * FRAME;
        #pragma unroll
        for (int j = 0; j < 9; ++j) {
            const int col = lane + j * 64;
            if (col < 544) {
                float v = 0.f;
                if (col < FRAME)          v = xr[col];
                else if (col < 2 * FRAME) v = cr[col - FRAME];
                bufA[w * 552 + col] = __float2bfloat16(v);
            }
        }
    }
    __syncthreads();

    // ---- Ph1: h1 = elu([x|c] @ We1 + eb1), M=256 (16 tiles); bufB=[x|h1] ----
    {
        const int col = 16 * w + ml;
        const bf16* wq = We1 + (size_t)col * 32 + quad * 8;   // u-stride 8192
        bf16x8 g0[6], g1[6], g2[5];
        #pragma unroll
        for (int j = 0; j < 6; ++j) g0[j] = *(const bf16x8*)(wq + (size_t)j * 8192);
        #pragma unroll
        for (int j = 0; j < 6; ++j) g1[j] = *(const bf16x8*)(wq + (size_t)(6 + j) * 8192);
        f32x4 acc = (f32x4){0,0,0,0};
        #pragma unroll
        for (int j = 0; j < 6; ++j)
            acc = MFMA(*(const bf16x8*)(bufA + ml * 552 + j * 32 + quad * 8), g0[j], acc);
        #pragma unroll
        for (int j = 0; j < 5; ++j) g2[j] = *(const bf16x8*)(wq + (size_t)(12 + j) * 8192);
        #pragma unroll
        for (int j = 0; j < 6; ++j)
            acc = MFMA(*(const bf16x8*)(bufA + ml * 552 + (6 + j) * 32 + quad * 8), g1[j], acc);
        #pragma unroll
        for (int j = 0; j < 5; ++j)
            acc = MFMA(*(const bf16x8*)(bufA + ml * 552 + (12 + j) * 32 + quad * 8), g2[j], acc);
        const float bv = eb1[col];
        #pragma unroll
        for (int rg = 0; rg < 4; ++rg)
            bufB[(quad * 4 + rg) * 552 + 267 + col] = __float2bfloat16(eluf(acc[rg] + bv));
        // copy x -> bufB[0..266] (row w); zero pad 523..543
        #pragma unroll
        for (int j = 0; j < 5; ++j) {
            const int cc = lane + j * 64;
            if (cc < 267) bufB[w * 552 + cc] = bufA[w * 552 + cc];
        }
        if (lane < 21) bufB[w * 552 + 523 + lane] = __float2bfloat16(0.f);
    }
    __syncthreads();

    // ---- Ph2: h2 = elu([x|h1] @ We2 + eb2) -> bufB in-place = [x|h2] ----
    {
        const int col = 16 * w + ml;
        const bf16* wq = We2 + (size_t)col * 32 + quad * 8;
        bf16x8 g0[6], g1[6], g2[5];
        #pragma unroll
        for (int j = 0; j < 6; ++j) g0[j] = *(const bf16x8*)(wq + (size_t)j * 8192);
        #pragma unroll
        for (int j = 0; j < 6; ++j) g1[j] = *(const bf16x8*)(wq + (size_t)(6 + j) * 8192);
        f32x4 acc = (f32x4){0,0,0,0};
        #pragma unroll
        for (int j = 0; j < 6; ++j)
            acc = MFMA(*(const bf16x8*)(bufB + ml * 552 + j * 32 + quad * 8), g0[j], acc);
        #pragma unroll
        for (int j = 0; j < 5; ++j) g2[j] = *(const bf16x8*)(wq + (size_t)(12 + j) * 8192);
        #pragma unroll
        for (int j = 0; j < 6; ++j)
            acc = MFMA(*(const bf16x8*)(bufB + ml * 552 + (6 + j) * 32 + quad * 8), g1[j], acc);
        #pragma unroll
        for (int j = 0; j < 5; ++j)
            acc = MFMA(*(const bf16x8*)(bufB + ml * 552 + (12 + j) * 32 + quad * 8), g2[j], acc);
        __syncthreads();   // all reads of bufB done before overwrite
        const float bv = eb2[col];
        #pragma unroll
        for (int rg = 0; rg < 4; ++rg)
            bufB[(quad * 4 + rg) * 552 + 267 + col] = __float2bfloat16(eluf(acc[rg] + bv));
    }
    __syncthreads();

    // ---- Ph3: mu|lv partial-K: wave w -> col tile (w&3), k-group (w>>2) ----
    {
        const int t = w & 3, kg = w >> 2;
        const int col = 16 * t + ml;
        const int k0 = kg * 4, k1 = (kg == 3) ? 17 : kg * 4 + 4;
        const bf16* wq = Wml + (size_t)col * 32 + quad * 8;   // u-stride 2048
        bf16x8 bm[5];
        #pragma unroll
        for (int u = 0; u < 5; ++u)
            if (k0 + u < k1) bm[u] = *(const bf16x8*)(wq + (size_t)(k0 + u) * 2048);
        f32x4 p = (f32x4){0,0,0,0};
        #pragma unroll
        for (int u = 0; u < 5; ++u) {
            const int ks = k0 + u;
            if (ks < k1)
                p = MFMA(*(const bf16x8*)(bufB + ml * 552 + ks * 32 + quad * 8), bm[u], p);
        }
        #pragma unroll
        for (int rg = 0; rg < 4; ++rg)
            sMLp[kg][(quad * 4 + rg) * 64 + col] = p[rg];
    }
    __syncthreads();

    // ---- Ph3b: z; bufB = [z|c] (Kpad 320); bufA[0..31] = z ----
    if (tid < 512) {
        const int r = tid >> 5, l = tid & 31;
        const float m  = sMLp[0][r * 64 + l] + sMLp[1][r * 64 + l]
                       + sMLp[2][r * 64 + l] + sMLp[3][r * 64 + l] + biasCat[l];
        const float lv = sMLp[0][r * 64 + 32 + l] + sMLp[1][r * 64 + 32 + l]
                       + sMLp[2][r * 64 + 32 + l] + sMLp[3][r * 64 + 32 + l] + biasCat[32 + l];
        const int gi = (row0 + r) * LATENT + l;
        out_mu[gi] = m; out_lv[gi] = lv;
        const bf16 zb = __float2bfloat16(m + eps[gi] * expf(0.5f * lv));
        bufA[r * 552 + l] = zb;       // prefix of [z|dh1]
        bufB[r * 552 + l] = zb;       // prefix of [z|c]
        #pragma unroll
        for (int j = 0; j < 9; ++j) {
            const int col = 32 + l + j * 32;          // 32..319
            bf16 v = __float2bfloat16(0.f);
            if (col < 299) v = bufA[r * 552 + 267 + (col - 32)];   // c
            bufB[r * 552 + col] = v;
        }
    }
    __syncthreads();

    // ---- Ph5: MoE layer 0 (experts 0-2 / 3-5) overlapped with gate ----
    {
        const int col = 16 * w + ml;
        const bf16* wq = W0 + (size_t)col * 32 + quad * 8;    // u = e*10+ks, stride 8192
        f32x4 pe[6] = {(f32x4){0,0,0,0}, (f32x4){0,0,0,0}, (f32x4){0,0,0,0},
                       (f32x4){0,0,0,0}, (f32x4){0,0,0,0}, (f32x4){0,0,0,0}};

        // pipelined 30-u chunk: 6 groups of 5, double-buffered named groups
        auto chunk30 = [&](int base) {
            bf16x8 ga[5], gb[5];
            #pragma unroll
            for (int j = 0; j < 5; ++j)
                ga[j] = *(const bf16x8*)(wq + (size_t)(base + j) * 8192);
            #pragma unroll
            for (int g = 0; g < 6; ++g) {
                if ((g & 1) == 0) {
                    if (g < 5) {
                        #pragma unroll
                        for (int j = 0; j < 5; ++j)
                            gb[j] = *(const bf16x8*)(wq + (size_t)(base + (g + 1) * 5 + j) * 8192);
                    }
                    #pragma unroll
                    for (int j = 0; j < 5; ++j) {
                        const int u = base + g * 5 + j;
                        pe[u / 10] = MFMA(*(const bf16x8*)(bufB + ml * 552 + (u % 10) * 32 + quad * 8),
                                          ga[j], pe[u / 10]);
                    }
                } else {
                    if (g < 5) {
                        #pragma unroll
                        for (int j = 0; j < 5; ++j)
                            ga[j] = *(const bf16x8*)(wq + (size_t)(base + (g + 1) * 5 + j) * 8192);
                    }
                    #pragma unroll
                    for (int j = 0; j < 5; ++j) {
                        const int u = base + g * 5 + j;
                        pe[u / 10] = MFMA(*(const bf16x8*)(bufB + ml * 552 + (u % 10) * 32 + quad * 8),
                                          gb[j], pe[u / 10]);
                    }
                }
            }
        };

        // chunk A: gate g1 (waves 0-3) + experts 0-2 (all waves), u = 0..29
        if (w < 4) {
            const int gc = 16 * w + ml;
            const bf16* gq = Wg0 + (size_t)gc * 32 + quad * 8;   // stride 2048
            f32x4 p = (f32x4){0,0,0,0};
            #pragma unroll
            for (int ks = 0; ks < 10; ++ks)
                p = MFMA(*(const bf16x8*)(bufB + ml * 552 + ks * 32 + quad * 8),
                         *(const bf16x8*)(gq + (size_t)ks * 2048), p);
            const float bv = gb0[gc];
            #pragma unroll
            for (int rg = 0; rg < 4; ++rg)
                sG1[(quad * 4 + rg) * 72 + gc] = __float2bfloat16(eluf(p[rg] + bv));
        }
        chunk30(0);
        __syncthreads();

        // chunk B: gate g2+logits+softmax (wave 0) + experts 3-5, u = 30..59
        if (w == 0) {
            #pragma unroll
            for (int t = 0; t < 4; ++t) {
                const int gc = 16 * t + ml;
                const bf16* gq = Wg1 + (size_t)gc * 32 + quad * 8;
                f32x4 p = (f32x4){0,0,0,0};
                #pragma unroll
                for (int ks = 0; ks < 2; ++ks)
                    p = MFMA(*(const bf16x8*)(sG1 + ml * 72 + ks * 32 + quad * 8),
                             *(const bf16x8*)(gq + (size_t)ks * 2048), p);
                const float bv = gb1[gc];
                #pragma unroll
                for (int rg = 0; rg < 4; ++rg)
                    sG2[(quad * 4 + rg) * 72 + gc] = __float2bfloat16(eluf(p[rg] + bv));
            }
            {
                const bf16* gq = Wg2 + (size_t)ml * 32 + quad * 8;   // stride 1024
                f32x4 p = (f32x4){0,0,0,0};
                #pragma unroll
                for (int ks = 0; ks < 2; ++ks)
                    p = MFMA(*(const bf16x8*)(sG2 + ml * 72 + ks * 32 + quad * 8),
                             *(const bf16x8*)(gq + (size_t)ks * 1024), p);
                const float bv = (ml < EXPERTS) ? gb2[ml] : 0.f;
                #pragma unroll
                for (int rg = 0; rg < 4; ++rg)
                    sLg[(quad * 4 + rg) * 16 + ml] = p[rg] + bv;
            }
            if (lane < 16) {   // softmax (same wave -> sLg visible via lgkmcnt)
                float v[EXPERTS];
                float m = -1e30f;
                #pragma unroll
                for (int i = 0; i < EXPERTS; ++i) { v[i] = sLg[lane * 16 + i]; m = fmaxf(m, v[i]); }
                float s = 0.f;
                #pragma unroll
                for (int i = 0; i < EXPERTS; ++i) { v[i] = expf(v[i] - m); s += v[i]; }
                const float inv = 1.f / s;
                #pragma unroll
                for (int i = 0; i < EXPERTS; ++i) sCo[i * 16 + lane] = v[i] * inv;
            }
        }
        chunk30(30);
        __syncthreads();   // sCo ready + all partials done

        f32x4 acc = (f32x4){0,0,0,0};
        #pragma unroll
        for (int e = 0; e < EXPERTS; ++e) {
            const float bv = b0[e * 256 + col];
            #pragma unroll
            for (int rg = 0; rg < 4; ++rg)
                acc[rg] += sCo[e * 16 + quad * 4 + rg] * (pe[e][rg] + bv);
        }
        #pragma unroll
        for (int rg = 0; rg < 4; ++rg)
            bufA[(quad * 4 + rg) * 552 + 32 + col] = __float2bfloat16(eluf(acc[rg]));
    }
    __syncthreads();

    // ---- Ph6: dh2 = elu(moe([z|dh1], W1, b1)), M=256 -> bufB = [z|dh2] ----
    {
        const int col = 16 * w + ml;
        const bf16* wq = W1 + (size_t)col * 32 + quad * 8;    // u = e*9+ks, stride 8192
        f32x4 pe[6] = {(f32x4){0,0,0,0}, (f32x4){0,0,0,0}, (f32x4){0,0,0,0},
                       (f32x4){0,0,0,0}, (f32x4){0,0,0,0}, (f32x4){0,0,0,0}};
        // 54 u's: 9 groups of 6, double-buffered
        bf16x8 ga[6], gb[6];
        #pragma unroll
        for (int j = 0; j < 6; ++j) ga[j] = *(const bf16x8*)(wq + (size_t)j * 8192);
        #pragma unroll
        for (int g = 0; g < 9; ++g) {
            if ((g & 1) == 0) {
                if (g < 8) {
                    #pragma unroll
                    for (int j = 0; j < 6; ++j)
                        gb[j] = *(const bf16x8*)(wq + (size_t)((g + 1) * 6 + j) * 8192);
                }
                #pragma unroll
                for (int j = 0; j < 6; ++j) {
                    const int u = g * 6 + j;
                    pe[u / 9] = MFMA(*(const bf16x8*)(bufA + ml * 552 + (u % 9) * 32 + quad * 8),
                                     ga[j], pe[u / 9]);
                }
            } else {
                if (g < 8) {
                    #pragma unroll
                    for (int j = 0; j < 6; ++j)
                        ga[j] = *(const bf16x8*)(wq + (size_t)((g + 1) * 6 + j) * 8192);
                }
                #pragma unroll
                for (int j = 0; j < 6; ++j) {
                    const int u = g * 6 + j;
                    pe[u / 9] = MFMA(*(const bf16x8*)(bufA + ml * 552 + (u % 9) * 32 + quad * 8),
                                     gb[j], pe[u / 9]);
                }
            }
        }
        f32x4 acc = (f32x4){0,0,0,0};
        #pragma unroll
        for (int e = 0; e < EXPERTS; ++e) {
            const float bv = b1[e * 256 + col];
            #pragma unroll
            for (int rg = 0; rg < 4; ++rg)
                acc[rg] += sCo[e * 16 + quad * 4 + rg] * (pe[e][rg] + bv);
        }
        // writes to bufB; its last reads were before the Ph5-end barrier
        #pragma unroll
        for (int rg = 0; rg < 4; ++rg)
            bufB[(quad * 4 + rg) * 552 + 32 + col] = __float2bfloat16(eluf(acc[rg]));
    }
    __syncthreads();

    // ---- Ph7: out = moe([z|dh2], W2, b2), M=267 (17 tiles) -> global ----
    {
        for (int t = w; t < 17; t += 16) {
            const int col = 16 * t + ml;
            const bf16* wq = W2 + (size_t)col * 32 + quad * 8;   // stride 10240
            f32x4 pe[6] = {(f32x4){0,0,0,0}, (f32x4){0,0,0,0}, (f32x4){0,0,0,0},
                           (f32x4){0,0,0,0}, (f32x4){0,0,0,0}, (f32x4){0,0,0,0}};
            bf16x8 ga[6], gb[6];
            #pragma unroll
            for (int j = 0; j < 6; ++j) ga[j] = *(const bf16x8*)(wq + (size_t)j * 10240);
            #pragma unroll
            for (int g = 0; g < 9; ++g) {
                if ((g & 1) == 0) {
                    if (g < 8) {
                        #pragma unroll
                        for (int j = 0; j < 6; ++j)
                            gb[j] = *(const bf16x8*)(wq + (size_t)((g + 1) * 6 + j) * 10240);
                    }
                    #pragma unroll
                    for (int j = 0; j < 6; ++j) {
                        const int u = g * 6 + j;
                        pe[u / 9] = MFMA(*(const bf16x8*)(bufB + ml * 552 + (u % 9) * 32 + quad * 8),
                                         ga[j], pe[u / 9]);
                    }
                } else {
                    if (g < 8) {
                        #pragma unroll
                        for (int j = 0; j < 6; ++j)
                            ga[j] = *(const bf16x8*)(wq + (size_t)((g + 1) * 6 + j) * 10240);
                    }
                    #pragma unroll
                    for (int j = 0; j < 6; ++j) {
                        const int u = g * 6 + j;
                        pe[u / 9] = MFMA(*(const bf16x8*)(bufB + ml * 552 + (u % 9) * 32 + quad * 8),
                                         gb[j], pe[u / 9]);
                    }
                }
            }
            f32x4 acc = (f32x4){0,0,0,0};
            #pragma unroll
            for (int e = 0; e < EXPERTS; ++e) {
                const float bv = (col < FRAME) ? b2[e * FRAME + col] : 0.f;
                #pragma unroll
                for (int rg = 0; rg < 4; ++rg)
                    acc[rg] += sCo[e * 16 + quad * 4 + rg] * (pe[e][rg] + bv);
            }
            if (col < FRAME) {
                #pragma unroll
                for (int rg = 0; rg < 4; ++rg)
                    out_layer[(size_t)(row0 + quad * 4 + rg) * FRAME + col] = acc[rg];
            }
        }
    }
}

// ---------------------------------------------------------------------------
extern "C" void kernel_launch(void* const* d_in, const int* in_sizes, int n_in,
                              void* d_out, int out_size, void* d_ws, size_t ws_size,
                              hipStream_t stream) {
    const float* x       = (const float*)d_in[0];
    const float* c       = (const float*)d_in[1];
    const float* eps     = (const float*)d_in[2];
    const float* enc_w1  = (const float*)d_in[3];
    const float* enc_b1  = (const float*)d_in[4];
    const float* enc_w2  = (const float*)d_in[5];
    const float* enc_b2  = (const float*)d_in[6];
    const float* enc_wmu = (const float*)d_in[7];
    const float* enc_bmu = (const float*)d_in[8];
    const float* enc_wlv = (const float*)d_in[9];
    const float* enc_blv = (const float*)d_in[10];
    const float* g_w0    = (const float*)d_in[11];
    const float* g_b0    = (const float*)d_in[12];
    const float* g_w1    = (const float*)d_in[13];
    const float* g_b1    = (const float*)d_in[14];
    const float* g_w2    = (const float*)d_in[15];
    const float* g_b2    = (const float*)d_in[16];
    const float* w0      = (const float*)d_in[17];
    const float* b0      = (const float*)d_in[18];
    const float* w1      = (const float*)d_in[19];
    const float* b1      = (const float*)d_in[20];
    const float* w2      = (const float*)d_in[21];
    const float* b2      = (const float*)d_in[22];

    // output (f32): [layer (4096x267) | mu (4096x32) | logvar (4096x32)]
    float* out_layer = (float*)d_out;
    float* out_mu    = out_layer + (size_t)N_BATCH * FRAME;
    float* out_lv    = out_mu    + (size_t)N_BATCH * LATENT;

    // ---- workspace layout (16B-aligned): biasCat + repacked weights only ----
    char* p = (char*)d_ws;
    float* biasCat = (float*)p;  p += 64 * 4;
    bf16* Wt_e1 = (bf16*)p;      p += (size_t)17 * 256 * 32 * 2;
    bf16* Wt_e2 = (bf16*)p;      p += (size_t)17 * 256 * 32 * 2;
    bf16* Wt_ml = (bf16*)p;      p += (size_t)17 * 64 * 32 * 2;
    bf16* Wt_g0 = (bf16*)p;      p += (size_t)10 * 64 * 32 * 2;
    bf16* Wt_g1 = (bf16*)p;      p += (size_t)2 * 64 * 32 * 2;
    bf16* Wt_g2 = (bf16*)p;      p += (size_t)2 * 32 * 32 * 2;
    bf16* Wt_w0 = (bf16*)p;      p += (size_t)EXPERTS * 10 * 256 * 32 * 2;
    bf16* Wt_w1 = (bf16*)p;      p += (size_t)EXPERTS * 9 * 256 * 32 * 2;
    bf16* Wt_w2 = (bf16*)p;      p += (size_t)EXPERTS * 9 * 320 * 32 * 2;

    WTab tab;
    int cum = 0, n = 0;
    auto add = [&](const float* src, bf16* dst, int K, int M, int Mtot, int mOff, int E) {
        int Ksteps;
        if (K == 534 || K == 523) Ksteps = 17;
        else if (K == 299) Ksteps = 10;
        else if (K == 288) Ksteps = 9;
        else Ksteps = 2;   // K=64
        const int Mtiles = (M + 31) / 32;
        tab.e[n] = {src, dst, K, M, Mtot, mOff, Ksteps, Mtiles, cum};
        cum += E * Ksteps * Mtiles;
        ++n;
    };
    add(enc_w1,  Wt_e1, 534, 256, 256, 0, 1);
    add(enc_w2,  Wt_e2, 523, 256, 256, 0, 1);
    add(enc_wmu, Wt_ml, 523, 32, 64, 0, 1);
    add(enc_wlv, Wt_ml, 523, 32, 64, 32, 1);
    add(g_w0,    Wt_g0, 299, 64, 64, 0, 1);
    add(g_w1,    Wt_g1, 64, 64, 64, 0, 1);
    add(g_w2,    Wt_g2, 64, 6, 32, 0, 1);
    add(w0,      Wt_w0, 299, 256, 256, 0, EXPERTS);
    add(w1,      Wt_w1, 288, 256, 256, 0, EXPERTS);
    add(w2,      Wt_w2, 288, 267, 320, 0, EXPERTS);
    tab.total = cum;

    // 0) prep: weight repack (cum blocks) + biasCat
    prep_kernel<<<dim3(cum), dim3(256), 0, stream>>>(enc_bmu, enc_blv, biasCat, tab);

    // 1) fully fused network: 256 blocks x 1024 threads (1 block/CU, 16 waves)
    fused_kernel<<<dim3(N_BATCH / 16), dim3(1024), 0, stream>>>(
        x, c, eps,
        Wt_e1, enc_b1, Wt_e2, enc_b2, Wt_ml, biasCat,
        Wt_g0, g_b0, Wt_g1, g_b1, Wt_g2, g_b2,
        Wt_w0, b0, Wt_w1, b1, Wt_w2, b2,
        out_layer, out_mu, out_lv);
}